// Round 10
// baseline (115.236 us; speedup 1.0000x reference)
//
#include <hip/hip_runtime.h>
#include <math.h>

#define DNUM 1024
#define CNUM 32000
#define NT 512             // 8 waves/block
#define GRID DNUM          // 1 row/block -> 1024 blocks -> 4 blocks/CU
#define KC 8               // coarse bins (0.675 sigma each)
#define KF 8               // fine bins   (0.084 sigma each)
#define NQ (CNUM / 4)      // 8000 4-class chunks

#define L2E 1.4426950408889634f
#define LN2 0.6931471805599453f

__device__ __forceinline__ float wave_red_sum(float v) {
    #pragma unroll
    for (int o = 32; o > 0; o >>= 1) v += __shfl_down(v, o, 64);
    return v;
}

// One block = 1 row, two streaming passes over L2-resident e1/e3.
// Histograms are PER-THREAD-PRIVATE LDS slots (plain read-add-write, no
// atomics; addr = bin*512 + tid is bank-conflict-free by construction).
// P1: moments + 8-bin coarse e2 partition over [-0.5σ, +4.9σ] of l2.
// P2: gap stats + 8-bin fine (e2,gap) partition of the crossing cell
// (exec-mask-skipped for ~99.6% of elements) + secant interpolation of the
// 0.5-cumsum crossing. Logits in log2 domain (coeffs pre-scaled by log2 e).
__global__ __launch_bounds__(NT, 8) void akl_rows(
    const float* __restrict__ h1, const float* __restrict__ e1,
    const float* __restrict__ h3, const float* __restrict__ e3,
    float* __restrict__ out)
{
    const int tid  = threadIdx.x;
    const int lane = tid & 63, wid = tid >> 6;   // 8 waves
    const int row  = blockIdx.x;

    __shared__ float hA[KC * NT];                // 16 KB: coarse e2 / fine e2
    __shared__ float hG[KF * NT];                // 16 KB: fine gap
    __shared__ float red[24];                    // wave partials
    __shared__ float shCS[KC];                   // coarse bin sums
    __shared__ float shFP[KF], shFG[KF];         // fine bin sums
    __shared__ float shA[10];  // iU1,iU2,thr,fkl,rkl,loS,icwF,c0F,Spre

    // Row coefficients, log2 domain (scalar, wave-uniform)
    const float a1L = h1[2*row] * L2E, b1L = h1[2*row+1] * L2E;
    const float a2L = h3[2*row] * L2E, b2L = h3[2*row+1] * L2E;
    // Safe analytic softmax shift (|l'| <= 6(|a'|+|b'|) w.h.p.)
    const float mh1L = 6.0f * (fabsf(a1L) + fabsf(b1L));
    const float mh2L = 6.0f * (fabsf(a2L) + fabsf(b2L));
    const float sp   = fmaxf(sqrtf(a2L*a2L + b2L*b2L), 1e-6f);
    const float icwC = 1.0f / (0.675f * sp);     // span [-0.5s, +4.9s], 8 cells
    const float C0C  = 0.5f / 0.675f;            // cbin = (int)fma(l2p,icwC,C0C)

    for (int i = tid; i < KC*NT; i += NT) hA[i] = 0.f;
    __syncthreads();                                                   // B0

    const float4* __restrict__ E1 = (const float4*)e1;
    const float4* __restrict__ E3 = (const float4*)e3;

    // ================= Pass 1: moments + coarse private-LDS partition =======
    float U1 = 0.f, S1 = 0.f, S2 = 0.f;
    {
        int j = tid;
        float4 A0 = E1[2*j], A1 = E1[2*j+1], B0 = E3[2*j], B1 = E3[2*j+1];
        while (true) {
            const int jn = j + NT;
            const bool more = jn < NQ;
            float4 C0, C1, D0, D1;
            if (more) { C0 = E1[2*jn]; C1 = E1[2*jn+1]; D0 = E3[2*jn]; D1 = E3[2*jn+1]; }
            float x1[4]={A0.x,A0.z,A1.x,A1.z}, y1[4]={A0.y,A0.w,A1.y,A1.w};
            float x3[4]={B0.x,B0.z,B1.x,B1.z}, y3[4]={B0.y,B0.w,B1.y,B1.w};
            #pragma unroll
            for (int k = 0; k < 4; k++) {
                float l1p = fmaf(a1L, x1[k], b1L*y1[k]);
                float l2p = fmaf(a2L, x3[k], b2L*y3[k]);
                float e1v = __builtin_amdgcn_exp2f(l1p - mh1L);
                float e2v = __builtin_amdgcn_exp2f(l2p - mh2L);
                float dp  = l2p - l1p;
                U1 += e1v;
                S1 = fmaf(e1v, dp, S1);
                S2 = fmaf(e2v, dp, S2);
                int cb = (int)fmaf(l2p, icwC, C0C);
                cb = min(KC-1, max(0, cb));
                hA[cb*NT + tid] += e2v;            // private: no race
            }
            if (!more) break;
            j = jn; A0 = C0; A1 = C1; B0 = D0; B1 = D1;
        }
    }
    {
        float u = wave_red_sum(U1);
        float s1 = wave_red_sum(S1);
        float s2 = wave_red_sum(S2);
        if (lane == 0) {
            red[wid*3 + 0] = u; red[wid*3 + 1] = s1; red[wid*3 + 2] = s2;
        }
    }
    __syncthreads();                                                   // B1

    // ---- Reduce coarse histogram: 8 groups x 32 lanes ----
    if (tid < KC*32) {
        int grp = tid >> 5, l32 = tid & 31;
        float s = 0.f;
        #pragma unroll
        for (int t = 0; t < NT/32; t++) s += hA[grp*NT + l32 + t*32];
        #pragma unroll
        for (int o = 16; o > 0; o >>= 1) s += __shfl_down(s, o, 32);
        if (l32 == 0) shCS[grp] = s;
    }
    __syncthreads();                                                   // B2

    // ---- Row params + coarse crossing cell (one thread) ----
    if (tid == 0) {
        float U1s = 0, S1s = 0, S2s = 0;
        for (int w = 0; w < 8; w++) {
            U1s += red[w*3 + 0]; S1s += red[w*3 + 1]; S2s += red[w*3 + 2];
        }
        float U2s = 0.f;
        #pragma unroll
        for (int i = 0; i < KC; i++) U2s += shCS[i];
        float M1 = mh1L + __builtin_amdgcn_logf(U1s);
        float M2 = mh2L + __builtin_amdgcn_logf(U2s);
        float delta = M2 - M1;
        float thr = 0.5f * U2s;
        float S = 0.f; int bsel = KC-1;
        for (int i = 0; i < KC; i++) {
            float m = shCS[i];
            if (S + m >= thr) { bsel = i; break; }
            S += m;
        }
        float wc  = 0.675f * sp;
        float loS = fmaf((float)bsel, wc, -0.5f*sp);
        float icwF = (float)KF / wc;
        shA[0] = 1.f / U1s;
        shA[1] = 1.f / U2s;
        shA[2] = thr;
        shA[3] = LN2 * (S2s/U2s - delta);    // fkl
        shA[4] = LN2 * (delta - S1s/U1s);    // rkl
        shA[5] = loS;
        shA[6] = icwF;
        shA[7] = -loS * icwF;                // c0F
        shA[8] = S;                          // Spre (unnorm prefix below cell)
    }
    // zero fine arrays (hA reused) after coarse reduce has consumed them
    for (int i = tid; i < KF*NT; i += NT) { hA[i] = 0.f; hG[i] = 0.f; }
    __syncthreads();                                                   // B3

    // ================= Pass 2: gap stats + fine private-LDS partition =======
    const float iU1l = shA[0], iU2l = shA[1];
    const float loSl = shA[5], icwFl = shA[6], c0Fl = shA[7];
    float gt = 0.f, Gpre = 0.f;
    {
        int j = tid;
        float4 A0 = E1[2*j], A1 = E1[2*j+1], B0 = E3[2*j], B1 = E3[2*j+1];
        while (true) {
            const int jn = j + NT;
            const bool more = jn < NQ;
            float4 C0, C1, D0, D1;
            if (more) { C0 = E1[2*jn]; C1 = E1[2*jn+1]; D0 = E3[2*jn]; D1 = E3[2*jn+1]; }
            float x1[4]={A0.x,A0.z,A1.x,A1.z}, y1[4]={A0.y,A0.w,A1.y,A1.w};
            float x3[4]={B0.x,B0.z,B1.x,B1.z}, y3[4]={B0.y,B0.w,B1.y,B1.w};
            #pragma unroll
            for (int k = 0; k < 4; k++) {
                float l1p = fmaf(a1L, x1[k], b1L*y1[k]);
                float l2p = fmaf(a2L, x3[k], b2L*y3[k]);
                float e1v = __builtin_amdgcn_exp2f(l1p - mh1L);
                float e2v = __builtin_amdgcn_exp2f(l2p - mh2L);
                float gap = fabsf(e2v*iU2l - e1v*iU1l);
                gt += gap;
                bool below = l2p < loSl;
                Gpre += below ? gap : 0.f;
                // trunc == floor for l2p >= loS (below-cell handled above)
                int fb = (int)fmaf(l2p, icwFl, c0Fl);
                if (!below && fb < KF) {   // ~0.4% of elements
                    int a = fb*NT + tid;
                    hA[a] += e2v;
                    hG[a] += gap;
                }
            }
            if (!more) break;
            j = jn; A0 = C0; A1 = C1; B0 = D0; B1 = D1;
        }
    }
    {
        float a = wave_red_sum(gt);
        float b = wave_red_sum(Gpre);
        if (lane == 0) { red[wid*2 + 0] = a; red[wid*2 + 1] = b; }
    }
    __syncthreads();                                                   // B4

    // ---- Reduce fine histograms: 16 groups x 32 lanes (8 for P, 8 for G) ----
    {
        int grp = tid >> 5, l32 = tid & 31;
        if (grp < KF) {
            float s = 0.f;
            #pragma unroll
            for (int t = 0; t < NT/32; t++) s += hA[grp*NT + l32 + t*32];
            #pragma unroll
            for (int o = 16; o > 0; o >>= 1) s += __shfl_down(s, o, 32);
            if (l32 == 0) shFP[grp] = s;
        } else {
            int g2 = grp - KF;
            float s = 0.f;
            #pragma unroll
            for (int t = 0; t < NT/32; t++) s += hG[g2*NT + l32 + t*32];
            #pragma unroll
            for (int o = 16; o > 0; o >>= 1) s += __shfl_down(s, o, 32);
            if (l32 == 0) shFG[g2] = s;
        }
    }
    __syncthreads();                                                   // B5

    // ---- Walk fine bins, secant-interpolate 0.5 crossing, output ----
    if (tid == 0) {
        float gts = 0, Gp = 0;
        for (int w = 0; w < 8; w++) { gts += red[w*2 + 0]; Gp += red[w*2 + 1]; }
        float thr = shA[2], fkl = shA[3], rkl = shA[4];
        float S = shA[8], G = Gp;
        bool done = false;
        #pragma unroll
        for (int i = 0; i < KF; i++) {
            if (!done) {
                float p = shFP[i], g = shFG[i];
                float ns = S + p;
                if (ns >= thr) {
                    float f = (thr - S) / fmaxf(p, 1e-30f);
                    f = fminf(fmaxf(f, 0.f), 1.f);
                    G += f * g;
                    done = true;
                } else { S = ns; G += g; }
            }
        }
        float gl = G;                    // g_tail
        float gh = gts - gl;             // g_head
        float akl = (gh*fkl + gl*rkl) / gts;
        unsafeAtomicAdd(out, akl * (1.0f/(float)DNUM));
    }
}

extern "C" void kernel_launch(void* const* d_in, const int* in_sizes, int n_in,
                              void* d_out, int out_size, void* d_ws, size_t ws_size,
                              hipStream_t stream) {
    const float* h1 = (const float*)d_in[0];
    const float* e1 = (const float*)d_in[1];
    const float* h3 = (const float*)d_in[2];
    const float* e3 = (const float*)d_in[3];
    hipMemsetAsync(d_out, 0, sizeof(float), stream);   // capture-safe
    akl_rows<<<GRID, NT, 0, stream>>>(h1, e1, h3, e3, (float*)d_out);
}

// Round 11
// 105.128 us; speedup vs baseline: 1.0962x; 1.0962x over previous
//
#include <hip/hip_runtime.h>
#include <math.h>

#define DNUM 1024
#define CNUM 32000
#define NT 512             // 8 waves/block
#define R 2                // rows per block
#define GRID (DNUM / R)    // 512 blocks -> 2 resident blocks/CU (grid-limited)
#define KC 8               // coarse bins (0.675 sigma each)
#define KF 8               // fine bins   (0.084 sigma each)
#define NQ (CNUM / 4)      // 8000 4-class chunks
#define NFULL (NQ / NT)    // 15 full iterations
#define TAILN (NQ - NFULL*NT) // 320

#define L2E 1.4426950408889634f
#define LN2 0.6931471805599453f

__device__ __forceinline__ float wave_red_sum(float v) {
    #pragma unroll
    for (int o = 32; o > 0; o >>= 1) v += __shfl_down(v, o, 64);
    return v;
}

// One block = 2 rows, two streaming passes over L2-resident e1/e3.
// Histograms: per-thread-private LDS slots, SPLIT ACROSS 4 DISTINCT __shared__
// ARRAYS (row x class-pair) so the compiler can interleave the read-add-write
// chains (no may-alias serialization). Logit shift folded into the FMA chain;
// Sigma e*d accumulated shifted and corrected exactly post-pass.
__global__ __launch_bounds__(NT, 4) void akl_rows(
    const float* __restrict__ h1, const float* __restrict__ e1,
    const float* __restrict__ h3, const float* __restrict__ e3,
    float* __restrict__ out)
{
    const int tid  = threadIdx.x;
    const int lane = tid & 63, wid = tid >> 6;   // 8 waves
    const int row0 = blockIdx.x * R;

    __shared__ float hC0[KC*NT];   // P1: row0 classes {0,1} | P2: fine e2 row0
    __shared__ float hC1[KC*NT];   // P1: row0 classes {2,3} | P2: fine e2 row1
    __shared__ float hC2[KC*NT];   // P1: row1 classes {0,1} | P2: fine gap row0
    __shared__ float hC3[KC*NT];   // P1: row1 classes {2,3} | P2: fine gap row1
    __shared__ float red[48];
    __shared__ float shCS[R*KC];
    __shared__ float shFP[R*KF], shFG[R*KF];
    __shared__ float shA[R][8];    // iU1,iU2,thr,fkl,rkl,icwF,c0Fs,Spre

    // Per-row coefficients, log2 domain
    float a1L[R], b1L[R], a2L[R], b2L[R], mh1L[R], mh2L[R], icwC[R], c0C[R];
    #pragma unroll
    for (int r = 0; r < R; r++) {
        a1L[r] = h1[2*(row0+r)] * L2E; b1L[r] = h1[2*(row0+r)+1] * L2E;
        a2L[r] = h3[2*(row0+r)] * L2E; b2L[r] = h3[2*(row0+r)+1] * L2E;
        mh1L[r] = 6.0f * (fabsf(a1L[r]) + fabsf(b1L[r]));   // safe shift
        mh2L[r] = 6.0f * (fabsf(a2L[r]) + fabsf(b2L[r]));
        float sp = fmaxf(sqrtf(a2L[r]*a2L[r] + b2L[r]*b2L[r]), 1e-6f);
        icwC[r] = 1.0f / (0.675f * sp);          // span [-0.5s, +4.9s], 8 cells
        // bin from SHIFTED logit l2s = l2p - mh2:  cb = (int)fma(l2s,icwC,c0C)
        c0C[r] = 0.5f/0.675f + mh2L[r]*icwC[r];
    }
    for (int i = tid; i < KC*NT; i += NT) {
        hC0[i] = 0.f; hC1[i] = 0.f; hC2[i] = 0.f; hC3[i] = 0.f;
    }
    __syncthreads();                                                   // B0

    const float4* __restrict__ E1 = (const float4*)e1;
    const float4* __restrict__ E3 = (const float4*)e3;

    // ================= Pass 1: moments + coarse split-array partition =======
    float U1[R] = {0,0}, S1p[R] = {0,0}, S2p[R] = {0,0};
    auto body1 = [&](int j) {
        float4 A0 = E1[2*j], A1 = E1[2*j+1], B0 = E3[2*j], B1 = E3[2*j+1];
        float x1[4]={A0.x,A0.z,A1.x,A1.z}, y1[4]={A0.y,A0.w,A1.y,A1.w};
        float x3[4]={B0.x,B0.z,B1.x,B1.z}, y3[4]={B0.y,B0.w,B1.y,B1.w};
        #pragma unroll
        for (int r = 0; r < R; r++) {
            #pragma unroll
            for (int k = 0; k < 4; k++) {
                float l1s = fmaf(a1L[r], x1[k], fmaf(b1L[r], y1[k], -mh1L[r]));
                float l2s = fmaf(a2L[r], x3[k], fmaf(b2L[r], y3[k], -mh2L[r]));
                float e1v = __builtin_amdgcn_exp2f(l1s);
                float e2v = __builtin_amdgcn_exp2f(l2s);
                float dps = l2s - l1s;              // corrected post-pass
                U1[r] += e1v;
                S1p[r] = fmaf(e1v, dps, S1p[r]);
                S2p[r] = fmaf(e2v, dps, S2p[r]);
                int cb = (int)fmaf(l2s, icwC[r], c0C[r]);
                cb = min(KC-1, max(0, cb));
                float* H = (r == 0) ? ((k < 2) ? hC0 : hC1)
                                    : ((k < 2) ? hC2 : hC3);
                H[cb*NT + tid] += e2v;              // private: no race
            }
        }
    };
    #pragma unroll 1
    for (int it = 0; it < NFULL; ++it) body1(it*NT + tid);
    if (tid < TAILN) body1(NFULL*NT + tid);

    #pragma unroll
    for (int r = 0; r < R; r++) {
        float u = wave_red_sum(U1[r]);
        float s1 = wave_red_sum(S1p[r]);
        float s2 = wave_red_sum(S2p[r]);
        if (lane == 0) {
            red[wid*6 + r*3 + 0] = u;
            red[wid*6 + r*3 + 1] = s1;
            red[wid*6 + r*3 + 2] = s2;
        }
    }
    __syncthreads();                                                   // B1

    // ---- Reduce coarse histogram: 16 groups (r x bin) x 32 lanes ----
    {
        int grp = tid >> 5, l32 = tid & 31;        // grp = r*KC + bin
        int r = grp >> 3, b = grp & 7;
        const float* Ha = r ? hC2 : hC0;
        const float* Hb = r ? hC3 : hC1;
        float s = 0.f;
        #pragma unroll
        for (int t = 0; t < NT/32; t++) {
            s += Ha[b*NT + l32 + t*32] + Hb[b*NT + l32 + t*32];
        }
        #pragma unroll
        for (int o = 16; o > 0; o >>= 1) s += __shfl_down(s, o, 64);
        if (l32 == 0) shCS[grp] = s;
    }
    __syncthreads();                                                   // B2

    // ---- Row params + coarse crossing cell (one thread per row) ----
    if (tid < R) {
        const int r = tid;
        float U1s = 0, S1s = 0, S2s = 0;
        for (int w = 0; w < 8; w++) {
            U1s += red[w*6 + r*3 + 0];
            S1s += red[w*6 + r*3 + 1];
            S2s += red[w*6 + r*3 + 2];
        }
        float U2s = 0.f;
        #pragma unroll
        for (int i = 0; i < KC; i++) U2s += shCS[r*KC + i];
        float mh1r = r ? mh1L[1] : mh1L[0];
        float mh2r = r ? mh2L[1] : mh2L[0];
        float a2r = r ? a2L[1] : a2L[0];
        float b2r = r ? b2L[1] : b2L[0];
        float dmh = mh2r - mh1r;
        S1s += dmh * U1s;                        // exact shift correction
        S2s += dmh * U2s;
        float M1 = mh1r + __builtin_amdgcn_logf(U1s);
        float M2 = mh2r + __builtin_amdgcn_logf(U2s);
        float delta = M2 - M1;
        float thr = 0.5f * U2s;
        float S = 0.f; int bsel = KC-1;
        for (int i = 0; i < KC; i++) {
            float m = shCS[r*KC + i];
            if (S + m >= thr) { bsel = i; break; }
            S += m;
        }
        float sp = fmaxf(sqrtf(a2r*a2r + b2r*b2r), 1e-6f);
        float wc  = 0.675f * sp;
        float loS_s = fmaf((float)bsel, wc, -0.5f*sp) - mh2r;  // shifted space
        float icwF = (float)KF / wc;
        shA[r][0] = 1.f / U1s;
        shA[r][1] = 1.f / U2s;
        shA[r][2] = thr;
        shA[r][3] = LN2 * (S2s/U2s - delta);     // fkl
        shA[r][4] = LN2 * (delta - S1s/U1s);     // rkl
        shA[r][5] = icwF;
        shA[r][6] = -loS_s * icwF;               // c0Fs: fb=floor(fma(l2s,icwF,c0Fs))
        shA[r][7] = S;                           // Spre (unnorm prefix below cell)
    }
    // re-zero for fine pass
    for (int i = tid; i < KF*NT; i += NT) {
        hC0[i] = 0.f; hC1[i] = 0.f; hC2[i] = 0.f; hC3[i] = 0.f;
    }
    __syncthreads();                                                   // B3

    // ================= Pass 2: gap stats + fine split-array partition =======
    float iU1l[R], iU2l[R], icwFl[R], c0Fl[R];
    #pragma unroll
    for (int r = 0; r < R; r++) {
        iU1l[r] = shA[r][0]; iU2l[r] = shA[r][1];
        icwFl[r] = shA[r][5]; c0Fl[r] = shA[r][6];
    }
    float gt[R] = {0,0}, Gpre[R] = {0,0};
    auto body2 = [&](int j) {
        float4 A0 = E1[2*j], A1 = E1[2*j+1], B0 = E3[2*j], B1 = E3[2*j+1];
        float x1[4]={A0.x,A0.z,A1.x,A1.z}, y1[4]={A0.y,A0.w,A1.y,A1.w};
        float x3[4]={B0.x,B0.z,B1.x,B1.z}, y3[4]={B0.y,B0.w,B1.y,B1.w};
        #pragma unroll
        for (int r = 0; r < R; r++) {
            #pragma unroll
            for (int k = 0; k < 4; k++) {
                float l1s = fmaf(a1L[r], x1[k], fmaf(b1L[r], y1[k], -mh1L[r]));
                float l2s = fmaf(a2L[r], x3[k], fmaf(b2L[r], y3[k], -mh2L[r]));
                float e1v = __builtin_amdgcn_exp2f(l1s);
                float e2v = __builtin_amdgcn_exp2f(l2s);
                float gap = fabsf(fmaf(e1v, -iU1l[r], e2v*iU2l[r]));
                gt[r] += gap;
                int fb = (int)floorf(fmaf(l2s, icwFl[r], c0Fl[r]));
                Gpre[r] += (fb < 0) ? gap : 0.f;
                if ((unsigned)fb < KF) {            // ~0.4% of elements
                    float* HP = r ? hC1 : hC0;
                    float* HG = r ? hC3 : hC2;
                    HP[fb*NT + tid] += e2v;
                    HG[fb*NT + tid] += gap;
                }
            }
        }
    };
    #pragma unroll 1
    for (int it = 0; it < NFULL; ++it) body2(it*NT + tid);
    if (tid < TAILN) body2(NFULL*NT + tid);

    #pragma unroll
    for (int r = 0; r < R; r++) {
        float a = wave_red_sum(gt[r]);
        float b = wave_red_sum(Gpre[r]);
        if (lane == 0) { red[wid*4 + r*2 + 0] = a; red[wid*4 + r*2 + 1] = b; }
    }
    __syncthreads();                                                   // B4

    // ---- Reduce fine histograms: 32 groups x 16 lanes ----
    {
        int grp = tid >> 4, l16 = tid & 15;      // 32 groups
        int isG = grp >> 4;                      // 0: P, 1: G
        int r = (grp >> 3) & 1, b = grp & 7;
        const float* H = isG ? (r ? hC3 : hC2) : (r ? hC1 : hC0);
        float s = 0.f;
        #pragma unroll
        for (int t = 0; t < NT/16; t++) s += H[b*NT + l16 + t*16];
        #pragma unroll
        for (int o = 8; o > 0; o >>= 1) s += __shfl_down(s, o, 64);
        if (l16 == 0) {
            if (isG) shFG[r*KF + b] = s; else shFP[r*KF + b] = s;
        }
    }
    __syncthreads();                                                   // B5

    // ---- Walk fine bins, secant-interpolate 0.5 crossing, output ----
    if (tid < R) {
        const int r = tid;
        float gts = 0, Gp = 0;
        for (int w = 0; w < 8; w++) {
            gts += red[w*4 + r*2 + 0];
            Gp  += red[w*4 + r*2 + 1];
        }
        float thr = shA[r][2], fkl = shA[r][3], rkl = shA[r][4];
        float S = shA[r][7], G = Gp;
        bool done = false;
        #pragma unroll
        for (int i = 0; i < KF; i++) {
            if (!done) {
                float p = shFP[r*KF + i], g = shFG[r*KF + i];
                float ns = S + p;
                if (ns >= thr) {
                    float f = (thr - S) / fmaxf(p, 1e-30f);
                    f = fminf(fmaxf(f, 0.f), 1.f);
                    G += f * g;
                    done = true;
                } else { S = ns; G += g; }
            }
        }
        float gl = G;                    // g_tail
        float gh = gts - gl;             // g_head
        float akl = (gh*fkl + gl*rkl) / gts;
        unsafeAtomicAdd(out, akl * (1.0f/(float)DNUM));
    }
}

extern "C" void kernel_launch(void* const* d_in, const int* in_sizes, int n_in,
                              void* d_out, int out_size, void* d_ws, size_t ws_size,
                              hipStream_t stream) {
    const float* h1 = (const float*)d_in[0];
    const float* e1 = (const float*)d_in[1];
    const float* h3 = (const float*)d_in[2];
    const float* e3 = (const float*)d_in[3];
    hipMemsetAsync(d_out, 0, sizeof(float), stream);   // capture-safe
    akl_rows<<<GRID, NT, 0, stream>>>(h1, e1, h3, e3, (float*)d_out);
}

// Round 12
// 104.692 us; speedup vs baseline: 1.1007x; 1.0042x over previous
//
#include <hip/hip_runtime.h>
#include <math.h>

#define DNUM 1024
#define CNUM 32000
#define NT 512             // 8 waves/block
#define R 2                // rows per block
#define GRID (DNUM / R)    // 512 blocks -> 2 resident blocks/CU
#define KC 8               // coarse bins (0.675 sigma each)
#define KF 8               // fine bins   (0.084 sigma each)
#define NQ (CNUM / 4)      // 8000 4-class chunks
#define NFULL (NQ / NT)    // 15 full iterations
#define TAILN (NQ - NFULL*NT) // 320

#define L2E 1.4426950408889634f
#define LN2 0.6931471805599453f

typedef float v2f __attribute__((ext_vector_type(2)));

__device__ __forceinline__ v2f splat2(float s) { v2f v; v.x = s; v.y = s; return v; }

__device__ __forceinline__ float wave_red_sum(float v) {
    #pragma unroll
    for (int o = 32; o > 0; o >>= 1) v += __shfl_down(v, o, 64);
    return v;
}

// One block = 2 rows, two streaming passes over L2-resident e1/e3.
// Histograms: per-thread-private LDS slots split across 4 distinct __shared__
// arrays (row x class-pair) -> no atomics, no races, bank-conflict-free.
// Class-PAIR packed fp32 arithmetic (ext_vector_type(2)) for pk_fma issue.
// Gap kept UNNORMALIZED (|e2 - c*e1|, c=U2/U1): akl is scale-invariant in gap.
__global__ __launch_bounds__(NT, 4) void akl_rows(
    const float* __restrict__ h1, const float* __restrict__ e1,
    const float* __restrict__ h3, const float* __restrict__ e3,
    float* __restrict__ out)
{
    const int tid  = threadIdx.x;
    const int lane = tid & 63, wid = tid >> 6;   // 8 waves
    const int row0 = blockIdx.x * R;

    __shared__ float hC0[KC*NT];   // P1: row0 pair0 | P2: fine e2  row0
    __shared__ float hC1[KC*NT];   // P1: row0 pair1 | P2: fine e2  row1
    __shared__ float hC2[KC*NT];   // P1: row1 pair0 | P2: fine gap row0
    __shared__ float hC3[KC*NT];   // P1: row1 pair1 | P2: fine gap row1
    __shared__ float red[48];
    __shared__ float shCS[R*KC];
    __shared__ float shFP[R*KF], shFG[R*KF];
    __shared__ float shA[R][7];    // c, thr, fkl, rkl, icwF, c0Fs, Spre

    // Per-row coefficients, log2 domain
    float a1L[R], b1L[R], a2L[R], b2L[R], mh1L[R], mh2L[R], icwC[R], c0C[R];
    #pragma unroll
    for (int r = 0; r < R; r++) {
        a1L[r] = h1[2*(row0+r)] * L2E; b1L[r] = h1[2*(row0+r)+1] * L2E;
        a2L[r] = h3[2*(row0+r)] * L2E; b2L[r] = h3[2*(row0+r)+1] * L2E;
        mh1L[r] = 6.0f * (fabsf(a1L[r]) + fabsf(b1L[r]));   // safe shift
        mh2L[r] = 6.0f * (fabsf(a2L[r]) + fabsf(b2L[r]));
        float sp = fmaxf(sqrtf(a2L[r]*a2L[r] + b2L[r]*b2L[r]), 1e-6f);
        icwC[r] = 1.0f / (0.675f * sp);          // span [-0.5s, +4.9s], 8 cells
        c0C[r] = 0.5f/0.675f + mh2L[r]*icwC[r];  // cb=(int)(l2s*icwC + c0C)
    }
    for (int i = tid; i < KC*NT; i += NT) {
        hC0[i] = 0.f; hC1[i] = 0.f; hC2[i] = 0.f; hC3[i] = 0.f;
    }
    __syncthreads();                                                   // B0

    const float4* __restrict__ E1 = (const float4*)e1;
    const float4* __restrict__ E3 = (const float4*)e3;

    // ================= Pass 1: moments + coarse split-array partition =======
    v2f U1v[R], S1v[R], S2v[R];
    #pragma unroll
    for (int r = 0; r < R; r++) { U1v[r] = splat2(0.f); S1v[r] = splat2(0.f); S2v[r] = splat2(0.f); }

    auto body1 = [&](int j) {
        float4 A0 = E1[2*j], A1 = E1[2*j+1], B0 = E3[2*j], B1 = E3[2*j+1];
        #pragma unroll
        for (int r = 0; r < R; r++) {
            const v2f a1v = splat2(a1L[r]), b1v = splat2(b1L[r]);
            const v2f a2v = splat2(a2L[r]), b2v = splat2(b2L[r]);
            const v2f m1v = splat2(-mh1L[r]), m2v = splat2(-mh2L[r]);
            const v2f icv = splat2(icwC[r]), c0v = splat2(c0C[r]);
            #pragma unroll
            for (int p = 0; p < 2; p++) {
                float4 A = p ? A1 : A0, B = p ? B1 : B0;
                v2f X1; X1.x = A.x; X1.y = A.z;
                v2f Y1; Y1.x = A.y; Y1.y = A.w;
                v2f X3; X3.x = B.x; X3.y = B.z;
                v2f Y3; Y3.x = B.y; Y3.y = B.w;
                v2f l1 = a1v*X1 + (b1v*Y1 + m1v);     // pk_fma x2
                v2f l2 = a2v*X3 + (b2v*Y3 + m2v);
                v2f e1v; e1v.x = __builtin_amdgcn_exp2f(l1.x);
                         e1v.y = __builtin_amdgcn_exp2f(l1.y);
                v2f e2v; e2v.x = __builtin_amdgcn_exp2f(l2.x);
                         e2v.y = __builtin_amdgcn_exp2f(l2.y);
                v2f dp = l2 - l1;                     // corrected post-pass
                U1v[r] += e1v;
                S1v[r] += e1v * dp;
                S2v[r] += e2v * dp;
                v2f t = l2*icv + c0v;
                float t0 = fminf(fmaxf(t.x, 0.f), 7.f);
                float t1 = fminf(fmaxf(t.y, 0.f), 7.f);
                int b0 = (int)t0, b1i = (int)t1;
                float* H = (r == 0) ? (p == 0 ? hC0 : hC1)
                                    : (p == 0 ? hC2 : hC3);
                H[b0*NT + tid]  += e2v.x;             // private: no race
                H[b1i*NT + tid] += e2v.y;
            }
        }
    };
    #pragma unroll 1
    for (int it = 0; it < NFULL; ++it) body1(it*NT + tid);
    if (tid < TAILN) body1(NFULL*NT + tid);

    #pragma unroll
    for (int r = 0; r < R; r++) {
        float u = wave_red_sum(U1v[r].x + U1v[r].y);
        float s1 = wave_red_sum(S1v[r].x + S1v[r].y);
        float s2 = wave_red_sum(S2v[r].x + S2v[r].y);
        if (lane == 0) {
            red[wid*6 + r*3 + 0] = u;
            red[wid*6 + r*3 + 1] = s1;
            red[wid*6 + r*3 + 2] = s2;
        }
    }
    __syncthreads();                                                   // B1

    // ---- Reduce coarse histogram: 16 groups (r x bin) x 32 lanes ----
    {
        int grp = tid >> 5, l32 = tid & 31;        // grp = r*KC + bin
        int r = grp >> 3, b = grp & 7;
        const float* Ha = r ? hC2 : hC0;
        const float* Hb = r ? hC3 : hC1;
        float s = 0.f;
        #pragma unroll
        for (int t = 0; t < NT/32; t++) {
            s += Ha[b*NT + l32 + t*32] + Hb[b*NT + l32 + t*32];
        }
        #pragma unroll
        for (int o = 16; o > 0; o >>= 1) s += __shfl_down(s, o, 64);
        if (l32 == 0) shCS[grp] = s;
    }
    __syncthreads();                                                   // B2

    // ---- Row params + coarse crossing cell (one thread per row) ----
    if (tid < R) {
        const int r = tid;
        float U1s = 0, S1s = 0, S2s = 0;
        for (int w = 0; w < 8; w++) {
            U1s += red[w*6 + r*3 + 0];
            S1s += red[w*6 + r*3 + 1];
            S2s += red[w*6 + r*3 + 2];
        }
        float U2s = 0.f;
        #pragma unroll
        for (int i = 0; i < KC; i++) U2s += shCS[r*KC + i];
        float mh1r = r ? mh1L[1] : mh1L[0];
        float mh2r = r ? mh2L[1] : mh2L[0];
        float a2r = r ? a2L[1] : a2L[0];
        float b2r = r ? b2L[1] : b2L[0];
        float dmh = mh2r - mh1r;
        S1s += dmh * U1s;                        // exact shift correction
        S2s += dmh * U2s;
        float M1 = mh1r + __builtin_amdgcn_logf(U1s);
        float M2 = mh2r + __builtin_amdgcn_logf(U2s);
        float delta = M2 - M1;
        float thr = 0.5f * U2s;
        float S = 0.f; int bsel = KC-1;
        for (int i = 0; i < KC; i++) {
            float m = shCS[r*KC + i];
            if (S + m >= thr) { bsel = i; break; }
            S += m;
        }
        float sp = fmaxf(sqrtf(a2r*a2r + b2r*b2r), 1e-6f);
        float wc  = 0.675f * sp;
        float loS_s = fmaf((float)bsel, wc, -0.5f*sp) - mh2r;  // shifted space
        float icwF = (float)KF / wc;
        shA[r][0] = U2s / U1s;                   // c (gap scale fold)
        shA[r][1] = thr;
        shA[r][2] = LN2 * (S2s/U2s - delta);     // fkl
        shA[r][3] = LN2 * (delta - S1s/U1s);     // rkl
        shA[r][4] = icwF;
        shA[r][5] = -loS_s * icwF;               // c0Fs: t=l2s*icwF+c0Fs
        shA[r][6] = S;                           // Spre (unnorm prefix below cell)
    }
    // re-zero for fine pass
    for (int i = tid; i < KF*NT; i += NT) {
        hC0[i] = 0.f; hC1[i] = 0.f; hC2[i] = 0.f; hC3[i] = 0.f;
    }
    __syncthreads();                                                   // B3

    // ================= Pass 2: gap stats + fine split-array partition =======
    float cR[R], icwFl[R], c0Fl[R];
    #pragma unroll
    for (int r = 0; r < R; r++) {
        cR[r] = shA[r][0]; icwFl[r] = shA[r][4]; c0Fl[r] = shA[r][5];
    }
    v2f gtv[R], Gpv[R];
    #pragma unroll
    for (int r = 0; r < R; r++) { gtv[r] = splat2(0.f); Gpv[r] = splat2(0.f); }

    auto body2 = [&](int j) {
        float4 A0 = E1[2*j], A1 = E1[2*j+1], B0 = E3[2*j], B1 = E3[2*j+1];
        #pragma unroll
        for (int r = 0; r < R; r++) {
            const v2f a1v = splat2(a1L[r]), b1v = splat2(b1L[r]);
            const v2f a2v = splat2(a2L[r]), b2v = splat2(b2L[r]);
            const v2f m1v = splat2(-mh1L[r]), m2v = splat2(-mh2L[r]);
            const v2f cv = splat2(-cR[r]);
            const v2f icv = splat2(icwFl[r]), c0v = splat2(c0Fl[r]);
            #pragma unroll
            for (int p = 0; p < 2; p++) {
                float4 A = p ? A1 : A0, B = p ? B1 : B0;
                v2f X1; X1.x = A.x; X1.y = A.z;
                v2f Y1; Y1.x = A.y; Y1.y = A.w;
                v2f X3; X3.x = B.x; X3.y = B.z;
                v2f Y3; Y3.x = B.y; Y3.y = B.w;
                v2f l1 = a1v*X1 + (b1v*Y1 + m1v);
                v2f l2 = a2v*X3 + (b2v*Y3 + m2v);
                v2f e1v; e1v.x = __builtin_amdgcn_exp2f(l1.x);
                         e1v.y = __builtin_amdgcn_exp2f(l1.y);
                v2f e2v; e2v.x = __builtin_amdgcn_exp2f(l2.x);
                         e2v.y = __builtin_amdgcn_exp2f(l2.y);
                v2f d = cv*e1v + e2v;                // e2 - c*e1 (pk_fma)
                v2f gap; gap.x = fabsf(d.x); gap.y = fabsf(d.y);
                gtv[r] += gap;
                v2f t = l2*icv + c0v;
                Gpv[r].x += (t.x < 0.f) ? gap.x : 0.f;
                Gpv[r].y += (t.y < 0.f) ? gap.y : 0.f;
                float* HP = r ? hC1 : hC0;
                float* HG = r ? hC3 : hC2;
                if (t.x >= 0.f && t.x < (float)KF) {   // ~0.4% of elements
                    int fb = (int)t.x;
                    HP[fb*NT + tid] += e2v.x;
                    HG[fb*NT + tid] += gap.x;
                }
                if (t.y >= 0.f && t.y < (float)KF) {
                    int fb = (int)t.y;
                    HP[fb*NT + tid] += e2v.y;
                    HG[fb*NT + tid] += gap.y;
                }
            }
        }
    };
    #pragma unroll 1
    for (int it = 0; it < NFULL; ++it) body2(it*NT + tid);
    if (tid < TAILN) body2(NFULL*NT + tid);

    #pragma unroll
    for (int r = 0; r < R; r++) {
        float a = wave_red_sum(gtv[r].x + gtv[r].y);
        float b = wave_red_sum(Gpv[r].x + Gpv[r].y);
        if (lane == 0) { red[wid*4 + r*2 + 0] = a; red[wid*4 + r*2 + 1] = b; }
    }
    __syncthreads();                                                   // B4

    // ---- Reduce fine histograms: 32 groups x 16 lanes ----
    {
        int grp = tid >> 4, l16 = tid & 15;      // 32 groups
        int isG = grp >> 4;                      // 0: P, 1: G
        int r = (grp >> 3) & 1, b = grp & 7;
        const float* H = isG ? (r ? hC3 : hC2) : (r ? hC1 : hC0);
        float s = 0.f;
        #pragma unroll
        for (int t = 0; t < NT/16; t++) s += H[b*NT + l16 + t*16];
        #pragma unroll
        for (int o = 8; o > 0; o >>= 1) s += __shfl_down(s, o, 64);
        if (l16 == 0) {
            if (isG) shFG[r*KF + b] = s; else shFP[r*KF + b] = s;
        }
    }
    __syncthreads();                                                   // B5

    // ---- Walk fine bins, secant-interpolate 0.5 crossing, output ----
    if (tid < R) {
        const int r = tid;
        float gts = 0, Gp = 0;
        for (int w = 0; w < 8; w++) {
            gts += red[w*4 + r*2 + 0];
            Gp  += red[w*4 + r*2 + 1];
        }
        float thr = shA[r][1], fkl = shA[r][2], rkl = shA[r][3];
        float S = shA[r][6], G = Gp;
        bool done = false;
        #pragma unroll
        for (int i = 0; i < KF; i++) {
            if (!done) {
                float p = shFP[r*KF + i], g = shFG[r*KF + i];
                float ns = S + p;
                if (ns >= thr) {
                    float f = (thr - S) / fmaxf(p, 1e-30f);
                    f = fminf(fmaxf(f, 0.f), 1.f);
                    G += f * g;
                    done = true;
                } else { S = ns; G += g; }
            }
        }
        float gl = G;                    // g_tail (unnormalized: scale cancels)
        float gh = gts - gl;             // g_head
        float akl = (gh*fkl + gl*rkl) / gts;
        unsafeAtomicAdd(out, akl * (1.0f/(float)DNUM));
    }
}

extern "C" void kernel_launch(void* const* d_in, const int* in_sizes, int n_in,
                              void* d_out, int out_size, void* d_ws, size_t ws_size,
                              hipStream_t stream) {
    const float* h1 = (const float*)d_in[0];
    const float* e1 = (const float*)d_in[1];
    const float* h3 = (const float*)d_in[2];
    const float* e3 = (const float*)d_in[3];
    hipMemsetAsync(d_out, 0, sizeof(float), stream);   // capture-safe
    akl_rows<<<GRID, NT, 0, stream>>>(h1, e1, h3, e3, (float*)d_out);
}

// Round 13
// 104.654 us; speedup vs baseline: 1.1011x; 1.0004x over previous
//
#include <hip/hip_runtime.h>
#include <math.h>

#define DNUM 1024
#define CNUM 32000
#define NT 512             // 8 waves/block
#define R 2                // rows per block
#define GRID (DNUM / R)    // 512 blocks -> 2 resident blocks/CU
#define KC 4               // coarse bins (1.35 sigma each), span [-0.5s, +4.9s]
#define KF 8               // fine bins   (0.169 sigma each)
#define NQ (CNUM / 4)      // 8000 4-class chunks
#define NFULL (NQ / NT)    // 15 full iterations
#define TAILN (NQ - NFULL*NT) // 320

#define L2E 1.4426950408889634f
#define LN2 0.6931471805599453f

typedef float v2f __attribute__((ext_vector_type(2)));

__device__ __forceinline__ v2f splat2(float s) { v2f v; v.x = s; v.y = s; return v; }

__device__ __forceinline__ float wave_red_sum(float v) {
    #pragma unroll
    for (int o = 32; o > 0; o >>= 1) v += __shfl_down(v, o, 64);
    return v;
}

// One block = 2 rows, two streaming passes over L2-resident e1/e3.
// P1 histogram: per-thread-private LDS slots in 8 FULLY-SEPARATE regions
// (row x class) -> exactly ONE read-add-write chain step per region per
// iteration: no may-alias serialization. KC=4 coarse bins, KF=8 fine bins,
// secant interpolation at the 0.5-cumsum crossing. Gap unnormalized
// (|e2 - c*e1|, c=U2/U1; akl is scale-invariant in gap). Logits in log2
// domain with the softmax shift folded into the FMA chain.
__global__ __launch_bounds__(NT, 4) void akl_rows(
    const float* __restrict__ h1, const float* __restrict__ e1,
    const float* __restrict__ h3, const float* __restrict__ e3,
    float* __restrict__ out)
{
    const int tid  = threadIdx.x;
    const int lane = tid & 63, wid = tid >> 6;   // 8 waves
    const int row0 = blockIdx.x * R;

    __shared__ float pool[16384];  // 64 KB
    // P1: region q = r*4 + class (q=0..7), base q*2048, slot = bin*512 + tid
    // P2: fine e2 row r: base r*4096; fine gap row r: base (2+r)*4096
    __shared__ float red[48];
    __shared__ float shCS[R*KC];
    __shared__ float shFP[R*KF], shFG[R*KF];
    __shared__ float shA[R][7];    // c, thr, fkl, rkl, icwF, c0Fs, Spre

    // Per-row coefficients, log2 domain
    float a1L[R], b1L[R], a2L[R], b2L[R], mh1L[R], mh2L[R], icwC[R], c0C[R];
    #pragma unroll
    for (int r = 0; r < R; r++) {
        a1L[r] = h1[2*(row0+r)] * L2E; b1L[r] = h1[2*(row0+r)+1] * L2E;
        a2L[r] = h3[2*(row0+r)] * L2E; b2L[r] = h3[2*(row0+r)+1] * L2E;
        mh1L[r] = 6.0f * (fabsf(a1L[r]) + fabsf(b1L[r]));   // safe shift
        mh2L[r] = 6.0f * (fabsf(a2L[r]) + fabsf(b2L[r]));
        float sp = fmaxf(sqrtf(a2L[r]*a2L[r] + b2L[r]*b2L[r]), 1e-6f);
        icwC[r] = 1.0f / (1.35f * sp);           // 4 cells over [-0.5s, +4.9s]
        c0C[r] = 0.5f/1.35f + mh2L[r]*icwC[r];   // cb=(int)(l2s*icwC + c0C)
    }
    for (int i = tid; i < 16384; i += NT) pool[i] = 0.f;
    __syncthreads();                                                   // B0

    const float4* __restrict__ E1 = (const float4*)e1;
    const float4* __restrict__ E3 = (const float4*)e3;

    // ================= Pass 1: moments + coarse 8-region partition ==========
    v2f U1v[R], S1v[R], S2v[R];
    #pragma unroll
    for (int r = 0; r < R; r++) { U1v[r] = splat2(0.f); S1v[r] = splat2(0.f); S2v[r] = splat2(0.f); }

    auto body1 = [&](int j) {
        float4 A0 = E1[2*j], A1 = E1[2*j+1], B0 = E3[2*j], B1 = E3[2*j+1];
        #pragma unroll
        for (int r = 0; r < R; r++) {
            const v2f a1v = splat2(a1L[r]), b1v = splat2(b1L[r]);
            const v2f a2v = splat2(a2L[r]), b2v = splat2(b2L[r]);
            const v2f m1v = splat2(-mh1L[r]), m2v = splat2(-mh2L[r]);
            const v2f icv = splat2(icwC[r]), c0v = splat2(c0C[r]);
            #pragma unroll
            for (int p = 0; p < 2; p++) {
                float4 A = p ? A1 : A0, B = p ? B1 : B0;
                v2f X1; X1.x = A.x; X1.y = A.z;
                v2f Y1; Y1.x = A.y; Y1.y = A.w;
                v2f X3; X3.x = B.x; X3.y = B.z;
                v2f Y3; Y3.x = B.y; Y3.y = B.w;
                v2f l1 = a1v*X1 + (b1v*Y1 + m1v);     // pk_fma
                v2f l2 = a2v*X3 + (b2v*Y3 + m2v);
                v2f e1v; e1v.x = __builtin_amdgcn_exp2f(l1.x);
                         e1v.y = __builtin_amdgcn_exp2f(l1.y);
                v2f e2v; e2v.x = __builtin_amdgcn_exp2f(l2.x);
                         e2v.y = __builtin_amdgcn_exp2f(l2.y);
                v2f dp = l2 - l1;                     // corrected post-pass
                U1v[r] += e1v;
                S1v[r] += e1v * dp;
                S2v[r] += e2v * dp;
                v2f t = l2*icv + c0v;
                float t0 = fminf(fmaxf(t.x, 0.f), 3.f);   // med3
                float t1 = fminf(fmaxf(t.y, 0.f), 3.f);
                int b0 = (int)t0, b1i = (int)t1;
                // one RMW per region per iteration: independent chains
                float* H0 = pool + (r*4 + 2*p    )*2048;
                float* H1 = pool + (r*4 + 2*p + 1)*2048;
                H0[b0*NT + tid]  += e2v.x;
                H1[b1i*NT + tid] += e2v.y;
            }
        }
    };
    #pragma unroll 1
    for (int it = 0; it < NFULL; ++it) body1(it*NT + tid);
    if (tid < TAILN) body1(NFULL*NT + tid);

    #pragma unroll
    for (int r = 0; r < R; r++) {
        float u = wave_red_sum(U1v[r].x + U1v[r].y);
        float s1 = wave_red_sum(S1v[r].x + S1v[r].y);
        float s2 = wave_red_sum(S2v[r].x + S2v[r].y);
        if (lane == 0) {
            red[wid*6 + r*3 + 0] = u;
            red[wid*6 + r*3 + 1] = s1;
            red[wid*6 + r*3 + 2] = s2;
        }
    }
    __syncthreads();                                                   // B1

    // ---- Reduce coarse histogram: 8 groups (r x bin) x 64 lanes ----
    {
        int grp = tid >> 6, l = tid & 63;          // grp = r*KC + bin
        int r = grp >> 2, b = grp & 3;
        float s = 0.f;
        #pragma unroll
        for (int c = 0; c < 4; c++) {
            const float* H = pool + (r*4 + c)*2048 + b*512;
            #pragma unroll
            for (int t = 0; t < 8; t++) s += H[l + t*64];
        }
        s = wave_red_sum(s);
        if (l == 0) shCS[grp] = s;
    }
    __syncthreads();                                                   // B2

    // ---- Row params + coarse crossing cell (one thread per row) ----
    if (tid < R) {
        const int r = tid;
        float U1s = 0, S1s = 0, S2s = 0;
        for (int w = 0; w < 8; w++) {
            U1s += red[w*6 + r*3 + 0];
            S1s += red[w*6 + r*3 + 1];
            S2s += red[w*6 + r*3 + 2];
        }
        float U2s = 0.f;
        #pragma unroll
        for (int i = 0; i < KC; i++) U2s += shCS[r*KC + i];
        float mh1r = r ? mh1L[1] : mh1L[0];
        float mh2r = r ? mh2L[1] : mh2L[0];
        float a2r = r ? a2L[1] : a2L[0];
        float b2r = r ? b2L[1] : b2L[0];
        float dmh = mh2r - mh1r;
        S1s += dmh * U1s;                        // exact shift correction
        S2s += dmh * U2s;
        float M1 = mh1r + __builtin_amdgcn_logf(U1s);
        float M2 = mh2r + __builtin_amdgcn_logf(U2s);
        float delta = M2 - M1;
        float thr = 0.5f * U2s;
        float S = 0.f; int bsel = KC-1;
        for (int i = 0; i < KC; i++) {
            float m = shCS[r*KC + i];
            if (S + m >= thr) { bsel = i; break; }
            S += m;
        }
        float sp = fmaxf(sqrtf(a2r*a2r + b2r*b2r), 1e-6f);
        float wc  = 1.35f * sp;                  // coarse cell width
        float loS_s = fmaf((float)bsel, wc, -0.5f*sp) - mh2r;  // shifted space
        float icwF = (float)KF / wc;
        shA[r][0] = U2s / U1s;                   // c (gap scale fold)
        shA[r][1] = thr;
        shA[r][2] = LN2 * (S2s/U2s - delta);     // fkl
        shA[r][3] = LN2 * (delta - S1s/U1s);     // rkl
        shA[r][4] = icwF;
        shA[r][5] = -loS_s * icwF;               // c0Fs: t=l2s*icwF+c0Fs
        shA[r][6] = S;                           // Spre (unnorm prefix below cell)
    }
    // re-zero pool for fine pass
    for (int i = tid; i < 16384; i += NT) pool[i] = 0.f;
    __syncthreads();                                                   // B3

    // ================= Pass 2: gap stats + fine partition ===================
    float cR[R], icwFl[R], c0Fl[R];
    #pragma unroll
    for (int r = 0; r < R; r++) {
        cR[r] = shA[r][0]; icwFl[r] = shA[r][4]; c0Fl[r] = shA[r][5];
    }
    v2f gtv[R], Gpv[R];
    #pragma unroll
    for (int r = 0; r < R; r++) { gtv[r] = splat2(0.f); Gpv[r] = splat2(0.f); }

    auto body2 = [&](int j) {
        float4 A0 = E1[2*j], A1 = E1[2*j+1], B0 = E3[2*j], B1 = E3[2*j+1];
        #pragma unroll
        for (int r = 0; r < R; r++) {
            const v2f a1v = splat2(a1L[r]), b1v = splat2(b1L[r]);
            const v2f a2v = splat2(a2L[r]), b2v = splat2(b2L[r]);
            const v2f m1v = splat2(-mh1L[r]), m2v = splat2(-mh2L[r]);
            const v2f cv = splat2(-cR[r]);
            const v2f icv = splat2(icwFl[r]), c0v = splat2(c0Fl[r]);
            float* HP = pool + r*4096;
            float* HG = pool + (2+r)*4096;
            #pragma unroll
            for (int p = 0; p < 2; p++) {
                float4 A = p ? A1 : A0, B = p ? B1 : B0;
                v2f X1; X1.x = A.x; X1.y = A.z;
                v2f Y1; Y1.x = A.y; Y1.y = A.w;
                v2f X3; X3.x = B.x; X3.y = B.z;
                v2f Y3; Y3.x = B.y; Y3.y = B.w;
                v2f l1 = a1v*X1 + (b1v*Y1 + m1v);
                v2f l2 = a2v*X3 + (b2v*Y3 + m2v);
                v2f e1v; e1v.x = __builtin_amdgcn_exp2f(l1.x);
                         e1v.y = __builtin_amdgcn_exp2f(l1.y);
                v2f e2v; e2v.x = __builtin_amdgcn_exp2f(l2.x);
                         e2v.y = __builtin_amdgcn_exp2f(l2.y);
                v2f d = cv*e1v + e2v;                // e2 - c*e1 (pk_fma)
                v2f gap; gap.x = fabsf(d.x); gap.y = fabsf(d.y);
                gtv[r] += gap;
                v2f t = l2*icv + c0v;
                Gpv[r].x += (t.x < 0.f) ? gap.x : 0.f;
                Gpv[r].y += (t.y < 0.f) ? gap.y : 0.f;
                if (t.x >= 0.f && t.x < (float)KF) {   // ~1% of elements
                    int fb = (int)t.x;
                    HP[fb*NT + tid] += e2v.x;
                    HG[fb*NT + tid] += gap.x;
                }
                if (t.y >= 0.f && t.y < (float)KF) {
                    int fb = (int)t.y;
                    HP[fb*NT + tid] += e2v.y;
                    HG[fb*NT + tid] += gap.y;
                }
            }
        }
    };
    #pragma unroll 1
    for (int it = 0; it < NFULL; ++it) body2(it*NT + tid);
    if (tid < TAILN) body2(NFULL*NT + tid);

    #pragma unroll
    for (int r = 0; r < R; r++) {
        float a = wave_red_sum(gtv[r].x + gtv[r].y);
        float b = wave_red_sum(Gpv[r].x + Gpv[r].y);
        if (lane == 0) { red[wid*4 + r*2 + 0] = a; red[wid*4 + r*2 + 1] = b; }
    }
    __syncthreads();                                                   // B4

    // ---- Reduce fine histograms: 32 groups x 16 lanes ----
    {
        int grp = tid >> 4, l16 = tid & 15;      // 32 groups
        int isG = grp >> 4;                      // 0: P, 1: G
        int r = (grp >> 3) & 1, b = grp & 7;
        const float* H = pool + (isG*2 + r)*4096 + b*512;
        float s = 0.f;
        #pragma unroll
        for (int t = 0; t < NT/16; t++) s += H[l16 + t*16];
        #pragma unroll
        for (int o = 8; o > 0; o >>= 1) s += __shfl_down(s, o, 64);
        if (l16 == 0) {
            if (isG) shFG[r*KF + b] = s; else shFP[r*KF + b] = s;
        }
    }
    __syncthreads();                                                   // B5

    // ---- Walk fine bins, secant-interpolate 0.5 crossing, output ----
    if (tid < R) {
        const int r = tid;
        float gts = 0, Gp = 0;
        for (int w = 0; w < 8; w++) {
            gts += red[w*4 + r*2 + 0];
            Gp  += red[w*4 + r*2 + 1];
        }
        float thr = shA[r][1], fkl = shA[r][2], rkl = shA[r][3];
        float S = shA[r][6], G = Gp;
        bool done = false;
        #pragma unroll
        for (int i = 0; i < KF; i++) {
            if (!done) {
                float p = shFP[r*KF + i], g = shFG[r*KF + i];
                float ns = S + p;
                if (ns >= thr) {
                    float f = (thr - S) / fmaxf(p, 1e-30f);
                    f = fminf(fmaxf(f, 0.f), 1.f);
                    G += f * g;
                    done = true;
                } else { S = ns; G += g; }
            }
        }
        float gl = G;                    // g_tail (unnormalized: scale cancels)
        float gh = gts - gl;             // g_head
        float akl = (gh*fkl + gl*rkl) / gts;
        unsafeAtomicAdd(out, akl * (1.0f/(float)DNUM));
    }
}

extern "C" void kernel_launch(void* const* d_in, const int* in_sizes, int n_in,
                              void* d_out, int out_size, void* d_ws, size_t ws_size,
                              hipStream_t stream) {
    const float* h1 = (const float*)d_in[0];
    const float* e1 = (const float*)d_in[1];
    const float* h3 = (const float*)d_in[2];
    const float* e3 = (const float*)d_in[3];
    hipMemsetAsync(d_out, 0, sizeof(float), stream);   // capture-safe
    akl_rows<<<GRID, NT, 0, stream>>>(h1, e1, h3, e3, (float*)d_out);
}